// Round 2
// baseline (343.605 us; speedup 1.0000x reference)
//
#include <hip/hip_runtime.h>

#define N_NODES 100000
#define N_EDGES 800000
#define FIN 64
#define HID 128
#define NB1 391   // ceil(N_NODES/256)
#define SRCS_CAP (N_EDGES + 7 * N_NODES)   // padded CSR capacity (pad to multiple of 8 per node)

typedef unsigned short ushort_t;
typedef __attribute__((ext_vector_type(8))) short short8;   // 8 bf16 = 4 VGPRs (MFMA A/B frag)
typedef __attribute__((ext_vector_type(16))) float fx16;    // 32x32 MFMA C/D frag
typedef __attribute__((ext_vector_type(4))) unsigned short us4;

__device__ inline ushort_t f2bf(float f) {   // RNE fp32 -> bf16
    unsigned u = __float_as_uint(f);
    u += 0x7fffu + ((u >> 16) & 1u);
    return (ushort_t)(u >> 16);
}
__device__ inline float bf2f(ushort_t h) { return __uint_as_float(((unsigned)h) << 16); }

// ---------------- utility ----------------
// zero deg + flag, fill padded srcs with sentinel row N_NODES (zero row)
__global__ void zero_int_kernel(int* __restrict__ deg, int* __restrict__ flag,
                                int* __restrict__ srcs) {
    int i = blockIdx.x * 256 + threadIdx.x;
    if (i < N_NODES) deg[i] = 0;
    if (i == 0) *flag = 0;
    for (int k = i; k < SRCS_CAP; k += NB1 * 256) srcs[k] = N_NODES;
}

// int32 vs int64 edge_index layout probe (int64 little-endian => odd words all 0)
__global__ void detect_kernel(const int* __restrict__ w, int* __restrict__ flag) {
    int i = blockIdx.x * 256 + threadIdx.x;
    if (i < 8192) {
        if (w[2 * i + 1] != 0) atomicOr(flag, 1);
    }
}

// ---------------- CSR build (padded to multiple of 8 per node) ----------------
__global__ void hist_kernel(const int* __restrict__ w, const int* __restrict__ flag,
                            int* __restrict__ deg, int* __restrict__ rank) {
    int e = blockIdx.x * 256 + threadIdx.x;
    if (e >= N_EDGES) return;
    int is32 = *flag;
    int d = is32 ? w[N_EDGES + e] : w[2 * (N_EDGES + e)];
    rank[e] = atomicAdd(&deg[d], 1);
}

__global__ void scan1_kernel(const int* __restrict__ deg, int* __restrict__ off,
                             int* __restrict__ bsums) {
    __shared__ int s[256];
    int t = threadIdx.x;
    int i = blockIdx.x * 256 + t;
    int v = (i < N_NODES) ? ((deg[i] + 7) & ~7) : 0;   // padded degree
    s[t] = v;
    __syncthreads();
    for (int d = 1; d < 256; d <<= 1) {
        int w = (t >= d) ? s[t - d] : 0;
        __syncthreads();
        s[t] += w;
        __syncthreads();
    }
    if (i < N_NODES) off[i] = s[t] - v;
    if (t == 255) bsums[blockIdx.x] = s[255];
}

__global__ void scan2_kernel(int* __restrict__ bsums) {
    __shared__ int s[512];
    int t = threadIdx.x;
    int v = (t < NB1) ? bsums[t] : 0;
    s[t] = v;
    __syncthreads();
    for (int d = 1; d < 512; d <<= 1) {
        int w = (t >= d) ? s[t - d] : 0;
        __syncthreads();
        s[t] += w;
        __syncthreads();
    }
    if (t < NB1) bsums[t] = s[t] - v;
    if (t == NB1 - 1) bsums[NB1] = s[t];   // total padded edge count
}

__global__ void scan3_kernel(int* __restrict__ off, const int* __restrict__ bsums) {
    int i = blockIdx.x * 256 + threadIdx.x;
    if (i < N_NODES) off[i] = off[i] + bsums[blockIdx.x];
    if (i == 0) off[N_NODES] = bsums[NB1];
}

__global__ void scatter_kernel(const int* __restrict__ w, const int* __restrict__ flag,
                               const int* __restrict__ off, const int* __restrict__ rank,
                               int* __restrict__ srcs) {
    int e = blockIdx.x * 256 + threadIdx.x;
    if (e >= N_EDGES) return;
    int is32 = *flag;
    int s = is32 ? w[e] : w[2 * e];
    int d = is32 ? w[N_EDGES + e] : w[2 * (N_EDGES + e)];
    srcs[off[d] + rank[e]] = s;
}

// ---------------- dtype conversion + sentinel zero rows ----------------
// Wb1[n][k], k<64 -> W1rel, else W1root. Wb2[n][k], k<128 -> W2rel, else W2root.
__global__ void cvt_kernel(const float* __restrict__ x, ushort_t* __restrict__ xb,
                           const float* __restrict__ W1rel, const float* __restrict__ W1root,
                           const float* __restrict__ W2rel, const float* __restrict__ W2root,
                           ushort_t* __restrict__ Wb1, ushort_t* __restrict__ Wb2,
                           ushort_t* __restrict__ h1b) {
    int i = blockIdx.x * 256 + threadIdx.x; // quad id for x
    if (i < N_NODES * FIN / 4) {
        float4 v = ((const float4*)x)[i];
        us4 o = {f2bf(v.x), f2bf(v.y), f2bf(v.z), f2bf(v.w)};
        ((us4*)xb)[i] = o;
    }
    us4 z = {0, 0, 0, 0};
    if (i < 16) ((us4*)xb)[(size_t)N_NODES * 16 + i] = z;          // xb zero row
    if (i >= 16 && i < 48) ((us4*)h1b)[(size_t)N_NODES * 32 + (i - 16)] = z;  // h1b zero row
    if (i < HID * HID) {
        int n = i >> 7, k = i & 127;
        float v = (k < FIN) ? W1rel[n * FIN + k] : W1root[n * FIN + (k - FIN)];
        Wb1[i] = f2bf(v);
    }
    if (i < HID * 2 * HID) {
        int n = i >> 8, k = i & 255;
        float v = (k < HID) ? W2rel[n * HID + k] : W2root[n * HID + (k - HID)];
        Wb2[i] = f2bf(v);
    }
}

// ------- fused: agg1 gather + MFMA GEMM layer 1: h1 = elu([agg1,x] @ Wb1^T + b1) -------
// LDS 32 KB: [0..16 KB) per-wave gather tiles (4 x 32 nodes x 64 feats bf16, XOR-swizzled),
// then (after barrier) whole region reused for Wb1 staging.
__global__ __launch_bounds__(256) void g1_kernel(
    const ushort_t* __restrict__ xb, const int* __restrict__ off,
    const int* __restrict__ srcs, const ushort_t* __restrict__ Wb1,
    const float* __restrict__ b1, ushort_t* __restrict__ h1b) {
    __shared__ ushort_t smem[16384];             // 32 KB
    int wave = threadIdx.x >> 6;
    int lane = threadIdx.x & 63;
    int half = lane >> 5, col = lane & 31;
    int nb = blockIdx.x * 128 + wave * 32;
    ushort_t* tile = smem + wave * 2048;         // 32 nodes x 64 feats

    // phase 1: gather-sum x over neighbors for this wave's 32 nodes (padded, maskless)
    {
        int g = lane >> 3, c = lane & 7;         // 8 edge slots x 8 chunks (16B) of 128B row
        const uint4* rows = (const uint4*)xb;    // 8 chunks per row (incl. zero row N)
        for (int j = 0; j < 32; j++) {
            int node = nb + j;
            if (node >= N_NODES) node = N_NODES - 1;
            int b = __builtin_amdgcn_readfirstlane(off[node]);
            int e = __builtin_amdgcn_readfirstlane(off[node + 1]);
            float acc[8];
#pragma unroll
            for (int k = 0; k < 8; k++) acc[k] = 0.f;
            for (int p = b; p < e; p += 8) {
                int s0 = srcs[p + g];
                uint4 A = rows[(size_t)s0 * 8 + c];
                acc[0] += __uint_as_float(A.x << 16);
                acc[1] += __uint_as_float(A.x & 0xffff0000u);
                acc[2] += __uint_as_float(A.y << 16);
                acc[3] += __uint_as_float(A.y & 0xffff0000u);
                acc[4] += __uint_as_float(A.z << 16);
                acc[5] += __uint_as_float(A.z & 0xffff0000u);
                acc[6] += __uint_as_float(A.w << 16);
                acc[7] += __uint_as_float(A.w & 0xffff0000u);
            }
#pragma unroll
            for (int k = 0; k < 8; k++) {
                acc[k] += __shfl_xor(acc[k], 8);
                acc[k] += __shfl_xor(acc[k], 16);
                acc[k] += __shfl_xor(acc[k], 32);
            }
            if (lane < 8) {
                unsigned w0 = (unsigned)f2bf(acc[0]) | ((unsigned)f2bf(acc[1]) << 16);
                unsigned w1 = (unsigned)f2bf(acc[2]) | ((unsigned)f2bf(acc[3]) << 16);
                unsigned w2 = (unsigned)f2bf(acc[4]) | ((unsigned)f2bf(acc[5]) << 16);
                unsigned w3 = (unsigned)f2bf(acc[6]) | ((unsigned)f2bf(acc[7]) << 16);
                uint4 o = {w0, w1, w2, w3};
                ((uint4*)(tile + j * 64))[lane ^ (j & 7)] = o;   // swizzled chunk slot
            }
        }
    }
    __syncthreads();

    // phase 2: A fragments — agg from LDS tile, x from global
    int nA = nb + col;
    if (nA >= N_NODES) nA = N_NODES - 1;
    short8 areg[8];
#pragma unroll
    for (int s = 0; s < 4; s++) {
        int cc = s * 2 + half;
        areg[s] = *(const short8*)(tile + col * 64 + ((cc ^ (col & 7)) << 3));
    }
#pragma unroll
    for (int s = 4; s < 8; s++)
        areg[s] = *(const short8*)(xb + (size_t)nA * FIN + (s - 4) * 16 + half * 8);
    __syncthreads();

    // phase 3: stage Wb1 (overwrites tiles)
#pragma unroll
    for (int it = 0; it < 8; it++) {
        int q = it * 256 + threadIdx.x;
        int n = q >> 4, cq = q & 15;
        short8 v = ((const short8*)Wb1)[q];
        *(short8*)(smem + n * HID + ((cq ^ (n & 7)) << 3)) = v;
    }
    __syncthreads();

    fx16 acc[4];
#pragma unroll
    for (int jt = 0; jt < 4; jt++)
#pragma unroll
        for (int r = 0; r < 16; r++) acc[jt][r] = 0.f;

#pragma unroll
    for (int s = 0; s < 8; s++) {
        int c = 2 * s + half;
#pragma unroll
        for (int jt = 0; jt < 4; jt++) {
            int n = jt * 32 + col;
            short8 bq = *(const short8*)(smem + n * HID + ((c ^ (n & 7)) << 3));
            acc[jt] = __builtin_amdgcn_mfma_f32_32x32x16_bf16(areg[s], bq, acc[jt], 0, 0, 0);
        }
    }
#pragma unroll
    for (int jt = 0; jt < 4; jt++) {
        int j = jt * 32 + col;
        float bias = b1[j];
#pragma unroll
        for (int r = 0; r < 16; r++) {
            int node = nb + (r & 3) + 8 * (r >> 2) + 4 * half;
            if (node < N_NODES) {
                float v = acc[jt][r] + bias;
                v = v > 0.f ? v : __expf(v) - 1.f;
                h1b[(size_t)node * HID + j] = f2bf(v);
            }
        }
    }
}

// ------- fused: agg2 gather + MFMA GEMM layer 2 + MFMA MLP head -------
// LDS (43008 B):
//   [0..32768)      per-wave gather tiles (4 x 32 nodes x 128 feats bf16, XOR-swizzled),
//                   then Wb2 K-half staging (two passes), then t2 tile (stride 136)
//   [34816..43008)  Wfc1 padded 32x128 bf16, XOR-swizzled (disjoint, staged once)
__global__ __launch_bounds__(256) void g2h_kernel(
    const ushort_t* __restrict__ h1b, const int* __restrict__ off,
    const int* __restrict__ srcs, const ushort_t* __restrict__ Wb2,
    const float* __restrict__ b2,
    const float* __restrict__ Wfc1, const float* __restrict__ bfc1,
    const float* __restrict__ Wfc2, const float* __restrict__ bfc2,
    float* __restrict__ out) {
    __shared__ ushort_t smem[21504];             // 43008 B
    ushort_t* wf = smem + 17408;                 // 4096 ushorts (8 KB), disjoint region

    // stage Wfc1b once (region never touched by tiles/Wb2/t2)
#pragma unroll
    for (int it = 0; it < 16; it++) {
        int idx = it * 256 + threadIdx.x;        // 0..4095
        int m = idx >> 7, k = idx & 127;
        float v = (m < 20) ? Wfc1[m * HID + k] : 0.f;
        wf[m * 128 + (((k >> 3) ^ (m & 7)) << 3) + (k & 7)] = f2bf(v);
    }

    int wave = threadIdx.x >> 6;
    int lane = threadIdx.x & 63;
    int half = lane >> 5, col = lane & 31;
    int nb = blockIdx.x * 128 + wave * 32;
    ushort_t* tile = smem + wave * 4096;         // 32 nodes x 128 feats

    // phase 1: gather-sum h1 over neighbors for this wave's 32 nodes (padded, maskless)
    {
        int g = lane >> 4, c = lane & 15;        // 4 edge slots x 16 chunks (16B) of 256B row
        const uint4* rows = (const uint4*)h1b;   // 16 chunks per row (incl. zero row N)
        for (int j = 0; j < 32; j++) {
            int node = nb + j;
            if (node >= N_NODES) node = N_NODES - 1;
            int b = __builtin_amdgcn_readfirstlane(off[node]);
            int e = __builtin_amdgcn_readfirstlane(off[node + 1]);
            float acc[8];
#pragma unroll
            for (int k = 0; k < 8; k++) acc[k] = 0.f;
            for (int p = b; p < e; p += 8) {
                int s0 = srcs[p + g];
                int s1 = srcs[p + 4 + g];
                uint4 A = rows[(size_t)s0 * 16 + c];
                uint4 B = rows[(size_t)s1 * 16 + c];
                acc[0] += __uint_as_float(A.x << 16) + __uint_as_float(B.x << 16);
                acc[1] += __uint_as_float(A.x & 0xffff0000u) + __uint_as_float(B.x & 0xffff0000u);
                acc[2] += __uint_as_float(A.y << 16) + __uint_as_float(B.y << 16);
                acc[3] += __uint_as_float(A.y & 0xffff0000u) + __uint_as_float(B.y & 0xffff0000u);
                acc[4] += __uint_as_float(A.z << 16) + __uint_as_float(B.z << 16);
                acc[5] += __uint_as_float(A.z & 0xffff0000u) + __uint_as_float(B.z & 0xffff0000u);
                acc[6] += __uint_as_float(A.w << 16) + __uint_as_float(B.w << 16);
                acc[7] += __uint_as_float(A.w & 0xffff0000u) + __uint_as_float(B.w & 0xffff0000u);
            }
#pragma unroll
            for (int k = 0; k < 8; k++) {
                acc[k] += __shfl_xor(acc[k], 16);
                acc[k] += __shfl_xor(acc[k], 32);
            }
            if (lane < 16) {
                unsigned w0 = (unsigned)f2bf(acc[0]) | ((unsigned)f2bf(acc[1]) << 16);
                unsigned w1 = (unsigned)f2bf(acc[2]) | ((unsigned)f2bf(acc[3]) << 16);
                unsigned w2 = (unsigned)f2bf(acc[4]) | ((unsigned)f2bf(acc[5]) << 16);
                unsigned w3 = (unsigned)f2bf(acc[6]) | ((unsigned)f2bf(acc[7]) << 16);
                uint4 o = {w0, w1, w2, w3};
                ((uint4*)(tile + j * 128))[lane ^ (j & 7)] = o;   // swizzled chunk slot
            }
        }
    }
    __syncthreads();

    // phase 2: A fragments — agg2 from LDS tile, h1 (own rows) from global
    int nA = nb + col;
    if (nA >= N_NODES) nA = N_NODES - 1;
    short8 areg[16];
#pragma unroll
    for (int s = 0; s < 8; s++) {
        int cc = s * 2 + half;
        areg[s] = *(const short8*)(tile + col * 128 + ((cc ^ (col & 7)) << 3));
    }
#pragma unroll
    for (int s = 8; s < 16; s++)
        areg[s] = *(const short8*)(h1b + (size_t)nA * HID + (s - 8) * 16 + half * 8);
    __syncthreads();

    // stage Wb2 K-half 0 (cols 0..127) — overwrites tiles
#pragma unroll
    for (int it = 0; it < 8; it++) {
        int q = it * 256 + threadIdx.x;          // 0..2047
        int n = q >> 4, cq = q & 15;
        short8 v = *(const short8*)(Wb2 + (size_t)n * 256 + cq * 8);
        *(short8*)(smem + n * 128 + ((cq ^ (n & 7)) << 3)) = v;
    }
    __syncthreads();

    fx16 acc[4];
#pragma unroll
    for (int jt = 0; jt < 4; jt++)
#pragma unroll
        for (int r = 0; r < 16; r++) acc[jt][r] = 0.f;

#pragma unroll
    for (int s = 0; s < 8; s++) {                // K 0..127 (agg2 part)
        int c = 2 * s + half;
#pragma unroll
        for (int jt = 0; jt < 4; jt++) {
            int n = jt * 32 + col;
            short8 bq = *(const short8*)(smem + n * 128 + ((c ^ (n & 7)) << 3));
            acc[jt] = __builtin_amdgcn_mfma_f32_32x32x16_bf16(areg[s], bq, acc[jt], 0, 0, 0);
        }
    }
    __syncthreads();
    // stage Wb2 K-half 1 (cols 128..255)
#pragma unroll
    for (int it = 0; it < 8; it++) {
        int q = it * 256 + threadIdx.x;
        int n = q >> 4, cq = q & 15;
        short8 v = *(const short8*)(Wb2 + (size_t)n * 256 + 128 + cq * 8);
        *(short8*)(smem + n * 128 + ((cq ^ (n & 7)) << 3)) = v;
    }
    __syncthreads();
#pragma unroll
    for (int s = 8; s < 16; s++) {               // K 128..255 (h1 part)
        int c = 2 * (s - 8) + half;
#pragma unroll
        for (int jt = 0; jt < 4; jt++) {
            int n = jt * 32 + col;
            short8 bq = *(const short8*)(smem + n * 128 + ((c ^ (n & 7)) << 3));
            acc[jt] = __builtin_amdgcn_mfma_f32_32x32x16_bf16(areg[s], bq, acc[jt], 0, 0, 0);
        }
    }
    __syncthreads();   // weights dead; reuse [0..34816) as t2 tile

    // t2 tile [node_local][feature], stride 136 ushorts
    ushort_t* tl = smem;
#pragma unroll
    for (int jt = 0; jt < 4; jt++) {
        int j = jt * 32 + col;
        float bias = b2[j];
#pragma unroll
        for (int r = 0; r < 16; r++) {
            int nl = wave * 32 + (r & 3) + 8 * (r >> 2) + 4 * half;
            tl[nl * 136 + j] = f2bf(acc[jt][r] + bias);
        }
    }
    __syncthreads();

    // fc1 as MFMA: A = t2 tile rows (node m = wave*32+col), B = Wfc1b (row col)
    short8 af[8];
#pragma unroll
    for (int s = 0; s < 8; s++)
        af[s] = *(const short8*)(tl + (wave * 32 + col) * 136 + s * 16 + half * 8);
    fx16 fa;
#pragma unroll
    for (int r = 0; r < 16; r++) fa[r] = 0.f;
#pragma unroll
    for (int s = 0; s < 8; s++) {
        int c = 2 * s + half;
        short8 bw = *(const short8*)(wf + col * 128 + ((c ^ (col & 7)) << 3));
        fa = __builtin_amdgcn_mfma_f32_32x32x16_bf16(af[s], bw, fa, 0, 0, 0);
    }
    // epilogue: relu(+bfc1) * Wfc2, butterfly-sum over the 32 output cols
    float biasv = (col < 20) ? bfc1[col] : 0.f;
    float w2v = (col < 20) ? Wfc2[col] : 0.f;
    float bz = bfc2[0];
    float red[16];
#pragma unroll
    for (int r = 0; r < 16; r++) {
        float v = fa[r] + biasv;
        v = (v > 0.f ? v : 0.f) * w2v;
        v += __shfl_xor(v, 1);
        v += __shfl_xor(v, 2);
        v += __shfl_xor(v, 4);
        v += __shfl_xor(v, 8);
        v += __shfl_xor(v, 16);
        red[r] = v;
    }
    if (col == 0) {
#pragma unroll
        for (int r = 0; r < 16; r++) {
            int nl = wave * 32 + (r & 3) + 8 * (r >> 2) + 4 * half;
            int ng = blockIdx.x * 128 + nl;
            if (ng < N_NODES) out[ng] = red[r] + bz;
        }
    }
}

// ---------------- launch ----------------
extern "C" void kernel_launch(void* const* d_in, const int* in_sizes, int n_in,
                              void* d_out, int out_size, void* d_ws, size_t ws_size,
                              hipStream_t stream) {
    const float* x = (const float*)d_in[0];
    const int* ei = (const int*)d_in[1];
    const float* W1rel = (const float*)d_in[2];
    const float* b1 = (const float*)d_in[3];
    const float* W1root = (const float*)d_in[4];
    const float* W2rel = (const float*)d_in[5];
    const float* b2 = (const float*)d_in[6];
    const float* W2root = (const float*)d_in[7];
    const float* Wfc1 = (const float*)d_in[8];
    const float* bfc1 = (const float*)d_in[9];
    const float* Wfc2 = (const float*)d_in[10];
    const float* bfc2 = (const float*)d_in[11];
    float* out = (float*)d_out;

    char* ws = (char*)d_ws;
    size_t o = 0;
    int* deg = (int*)(ws + o);       o += (size_t)N_NODES * 4;
    int* off = (int*)(ws + o);       o += (size_t)(N_NODES + 1) * 4 + 12;
    int* bsums = (int*)(ws + o);     o += 4096;
    int* flag = (int*)(ws + o);      o += 16;
    int* rank = (int*)(ws + o);      o += (size_t)N_EDGES * 4;                // 3.2 MB
    int* srcs = (int*)(ws + o);      o += (size_t)SRCS_CAP * 4;               // 6.0 MB
    ushort_t* xb = (ushort_t*)(ws + o);  o += (size_t)(N_NODES + 1) * FIN * 2;  // 12.8 MB (+zero row)
    ushort_t* h1b = (ushort_t*)(ws + o); o += (size_t)(N_NODES + 1) * HID * 2;  // 25.6 MB (+zero row)
    ushort_t* Wb1 = (ushort_t*)(ws + o); o += (size_t)HID * HID * 2;            // 32 KB
    ushort_t* Wb2 = (ushort_t*)(ws + o); o += (size_t)HID * 2 * HID * 2;        // 64 KB

    const int GW = (N_NODES + 127) / 128; // 782 blocks: 4 waves x 32 nodes

    zero_int_kernel<<<NB1, 256, 0, stream>>>(deg, flag, srcs);
    detect_kernel<<<32, 256, 0, stream>>>(ei, flag);
    hist_kernel<<<(N_EDGES + 255) / 256, 256, 0, stream>>>(ei, flag, deg, rank);
    scan1_kernel<<<NB1, 256, 0, stream>>>(deg, off, bsums);
    scan2_kernel<<<1, 512, 0, stream>>>(bsums);
    scan3_kernel<<<NB1, 256, 0, stream>>>(off, bsums);
    scatter_kernel<<<(N_EDGES + 255) / 256, 256, 0, stream>>>(ei, flag, off, rank, srcs);
    cvt_kernel<<<(N_NODES * FIN / 4 + 255) / 256, 256, 0, stream>>>(
        x, xb, W1rel, W1root, W2rel, W2root, Wb1, Wb2, h1b);
    g1_kernel<<<GW, 256, 0, stream>>>(xb, off, srcs, Wb1, b1, h1b);
    g2h_kernel<<<GW, 256, 0, stream>>>(h1b, off, srcs, Wb2, b2, Wfc1, bfc1, Wfc2, bfc2, out);
}

// Round 3
// 278.209 us; speedup vs baseline: 1.2351x; 1.2351x over previous
//
#include <hip/hip_runtime.h>

#define N_NODES 100000
#define N_EDGES 800000
#define FIN 64
#define HID 128
#define NB1 391   // ceil(N_NODES/256)
#define SRCS_CAP (N_EDGES + 7 * N_NODES)   // padded CSR capacity (pad to multiple of 8 per node)

typedef unsigned short ushort_t;
typedef __attribute__((ext_vector_type(8))) short short8;   // 8 bf16 = 4 VGPRs (MFMA A/B frag)
typedef __attribute__((ext_vector_type(16))) float fx16;    // 32x32 MFMA C/D frag
typedef __attribute__((ext_vector_type(4))) unsigned short us4;

__device__ inline ushort_t f2bf(float f) {   // RNE fp32 -> bf16
    unsigned u = __float_as_uint(f);
    u += 0x7fffu + ((u >> 16) & 1u);
    return (ushort_t)(u >> 16);
}
__device__ inline float bf2f(ushort_t h) { return __uint_as_float(((unsigned)h) << 16); }

// ---------------- utility ----------------
// zero deg + flag, fill padded srcs with sentinel row N_NODES (zero row)
__global__ void zero_int_kernel(int* __restrict__ deg, int* __restrict__ flag,
                                int* __restrict__ srcs) {
    int i = blockIdx.x * 256 + threadIdx.x;
    if (i < N_NODES) deg[i] = 0;
    if (i == 0) *flag = 0;
    for (int k = i; k < SRCS_CAP; k += NB1 * 256) srcs[k] = N_NODES;
}

// int32 vs int64 edge_index layout probe (int64 little-endian => odd words all 0)
__global__ void detect_kernel(const int* __restrict__ w, int* __restrict__ flag) {
    int i = blockIdx.x * 256 + threadIdx.x;
    if (i < 8192) {
        if (w[2 * i + 1] != 0) atomicOr(flag, 1);
    }
}

// ---------------- CSR build (padded to multiple of 8 per node) ----------------
__global__ void hist_kernel(const int* __restrict__ w, const int* __restrict__ flag,
                            int* __restrict__ deg, int* __restrict__ rank) {
    int e = blockIdx.x * 256 + threadIdx.x;
    if (e >= N_EDGES) return;
    int is32 = *flag;
    int d = is32 ? w[N_EDGES + e] : w[2 * (N_EDGES + e)];
    rank[e] = atomicAdd(&deg[d], 1);
}

__global__ void scan1_kernel(const int* __restrict__ deg, int* __restrict__ off,
                             int* __restrict__ bsums) {
    __shared__ int s[256];
    int t = threadIdx.x;
    int i = blockIdx.x * 256 + t;
    int v = (i < N_NODES) ? ((deg[i] + 7) & ~7) : 0;   // padded degree
    s[t] = v;
    __syncthreads();
    for (int d = 1; d < 256; d <<= 1) {
        int w = (t >= d) ? s[t - d] : 0;
        __syncthreads();
        s[t] += w;
        __syncthreads();
    }
    if (i < N_NODES) off[i] = s[t] - v;
    if (t == 255) bsums[blockIdx.x] = s[255];
}

__global__ void scan2_kernel(int* __restrict__ bsums) {
    __shared__ int s[512];
    int t = threadIdx.x;
    int v = (t < NB1) ? bsums[t] : 0;
    s[t] = v;
    __syncthreads();
    for (int d = 1; d < 512; d <<= 1) {
        int w = (t >= d) ? s[t - d] : 0;
        __syncthreads();
        s[t] += w;
        __syncthreads();
    }
    if (t < NB1) bsums[t] = s[t] - v;
    if (t == NB1 - 1) bsums[NB1] = s[t];   // total padded edge count
}

__global__ void scan3_kernel(int* __restrict__ off, const int* __restrict__ bsums) {
    int i = blockIdx.x * 256 + threadIdx.x;
    if (i < N_NODES) off[i] = off[i] + bsums[blockIdx.x];
    if (i == 0) off[N_NODES] = bsums[NB1];
}

__global__ void scatter_kernel(const int* __restrict__ w, const int* __restrict__ flag,
                               const int* __restrict__ off, const int* __restrict__ rank,
                               int* __restrict__ srcs) {
    int e = blockIdx.x * 256 + threadIdx.x;
    if (e >= N_EDGES) return;
    int is32 = *flag;
    int s = is32 ? w[e] : w[2 * e];
    int d = is32 ? w[N_EDGES + e] : w[2 * (N_EDGES + e)];
    srcs[off[d] + rank[e]] = s;
}

// ---------------- dtype conversion + sentinel zero rows ----------------
// Wb1[n][k], k<64 -> W1rel, else W1root. Wb2[n][k], k<128 -> W2rel, else W2root.
__global__ void cvt_kernel(const float* __restrict__ x, ushort_t* __restrict__ xb,
                           const float* __restrict__ W1rel, const float* __restrict__ W1root,
                           const float* __restrict__ W2rel, const float* __restrict__ W2root,
                           ushort_t* __restrict__ Wb1, ushort_t* __restrict__ Wb2,
                           ushort_t* __restrict__ h1b) {
    int i = blockIdx.x * 256 + threadIdx.x; // quad id for x
    if (i < N_NODES * FIN / 4) {
        float4 v = ((const float4*)x)[i];
        us4 o = {f2bf(v.x), f2bf(v.y), f2bf(v.z), f2bf(v.w)};
        ((us4*)xb)[i] = o;
    }
    us4 z = {0, 0, 0, 0};
    if (i < 16) ((us4*)xb)[(size_t)N_NODES * 16 + i] = z;          // xb zero row
    if (i >= 16 && i < 48) ((us4*)h1b)[(size_t)N_NODES * 32 + (i - 16)] = z;  // h1b zero row
    if (i < HID * HID) {
        int n = i >> 7, k = i & 127;
        float v = (k < FIN) ? W1rel[n * FIN + k] : W1root[n * FIN + (k - FIN)];
        Wb1[i] = f2bf(v);
    }
    if (i < HID * 2 * HID) {
        int n = i >> 8, k = i & 255;
        float v = (k < HID) ? W2rel[n * HID + k] : W2root[n * HID + (k - HID)];
        Wb2[i] = f2bf(v);
    }
}

// ------- aggregation: wave per node, slot-parallel vectorized gather (maskless, padded) -------
__global__ void agg1_kernel(const ushort_t* __restrict__ xb, const int* __restrict__ off,
                            const int* __restrict__ srcs, ushort_t* __restrict__ aggb) {
    int wid = (blockIdx.x * 256 + threadIdx.x) >> 6; // node
    int lane = threadIdx.x & 63;
    if (wid >= N_NODES) return;
    int b = __builtin_amdgcn_readfirstlane(off[wid]);
    int e = __builtin_amdgcn_readfirstlane(off[wid + 1]);
    unsigned g = lane >> 3;   // edge slot 0..7
    unsigned c = lane & 7;    // 16B chunk of the 128B row
    float acc[8];
#pragma unroll
    for (int j = 0; j < 8; j++) acc[j] = 0.f;
    const uint4* rows = (const uint4*)xb;    // 8 chunks per row (incl. zero row N)
    for (int p = b; p < e; p += 8) {
        unsigned s0 = (unsigned)srcs[p + g];     // padding => always valid (sentinel = zero row)
        uint4 A = rows[s0 * 8u + c];
        acc[0] += __uint_as_float(A.x << 16);
        acc[1] += __uint_as_float(A.x & 0xffff0000u);
        acc[2] += __uint_as_float(A.y << 16);
        acc[3] += __uint_as_float(A.y & 0xffff0000u);
        acc[4] += __uint_as_float(A.z << 16);
        acc[5] += __uint_as_float(A.z & 0xffff0000u);
        acc[6] += __uint_as_float(A.w << 16);
        acc[7] += __uint_as_float(A.w & 0xffff0000u);
    }
#pragma unroll
    for (int j = 0; j < 8; j++) {
        acc[j] += __shfl_xor(acc[j], 8);
        acc[j] += __shfl_xor(acc[j], 16);
        acc[j] += __shfl_xor(acc[j], 32);
    }
    if (lane < 8) {
        unsigned w0 = (unsigned)f2bf(acc[0]) | ((unsigned)f2bf(acc[1]) << 16);
        unsigned w1 = (unsigned)f2bf(acc[2]) | ((unsigned)f2bf(acc[3]) << 16);
        unsigned w2 = (unsigned)f2bf(acc[4]) | ((unsigned)f2bf(acc[5]) << 16);
        unsigned w3 = (unsigned)f2bf(acc[6]) | ((unsigned)f2bf(acc[7]) << 16);
        uint4 o = {w0, w1, w2, w3};
        ((uint4*)(aggb + (size_t)wid * FIN))[lane] = o;
    }
}

__global__ void agg2_kernel(const ushort_t* __restrict__ h1b, const int* __restrict__ off,
                            const int* __restrict__ srcs, ushort_t* __restrict__ aggb) {
    int wid = (blockIdx.x * 256 + threadIdx.x) >> 6; // node
    int lane = threadIdx.x & 63;
    if (wid >= N_NODES) return;
    int b = __builtin_amdgcn_readfirstlane(off[wid]);
    int e = __builtin_amdgcn_readfirstlane(off[wid + 1]);
    unsigned g = lane >> 4;   // edge slot 0..3
    unsigned c = lane & 15;   // 16B chunk of the 256B row
    float acc[8];
#pragma unroll
    for (int j = 0; j < 8; j++) acc[j] = 0.f;
    const uint4* rows = (const uint4*)h1b;   // 16 chunks per row (incl. zero row N)
    for (int p = b; p < e; p += 8) {
        unsigned s0 = (unsigned)srcs[p + g];
        unsigned s1 = (unsigned)srcs[p + 4 + g];
        uint4 A = rows[s0 * 16u + c];
        uint4 B = rows[s1 * 16u + c];
        acc[0] += __uint_as_float(A.x << 16) + __uint_as_float(B.x << 16);
        acc[1] += __uint_as_float(A.x & 0xffff0000u) + __uint_as_float(B.x & 0xffff0000u);
        acc[2] += __uint_as_float(A.y << 16) + __uint_as_float(B.y << 16);
        acc[3] += __uint_as_float(A.y & 0xffff0000u) + __uint_as_float(B.y & 0xffff0000u);
        acc[4] += __uint_as_float(A.z << 16) + __uint_as_float(B.z << 16);
        acc[5] += __uint_as_float(A.z & 0xffff0000u) + __uint_as_float(B.z & 0xffff0000u);
        acc[6] += __uint_as_float(A.w << 16) + __uint_as_float(B.w << 16);
        acc[7] += __uint_as_float(A.w & 0xffff0000u) + __uint_as_float(B.w & 0xffff0000u);
    }
#pragma unroll
    for (int j = 0; j < 8; j++) {
        acc[j] += __shfl_xor(acc[j], 16);
        acc[j] += __shfl_xor(acc[j], 32);
    }
    if (lane < 16) {
        unsigned w0 = (unsigned)f2bf(acc[0]) | ((unsigned)f2bf(acc[1]) << 16);
        unsigned w1 = (unsigned)f2bf(acc[2]) | ((unsigned)f2bf(acc[3]) << 16);
        unsigned w2 = (unsigned)f2bf(acc[4]) | ((unsigned)f2bf(acc[5]) << 16);
        unsigned w3 = (unsigned)f2bf(acc[6]) | ((unsigned)f2bf(acc[7]) << 16);
        uint4 o = {w0, w1, w2, w3};
        ((uint4*)(aggb + (size_t)wid * HID))[lane] = o;
    }
}

// ------- MFMA GEMM layer 1: h1 = elu([agg1,x] @ Wb1^T + b1) -------
__global__ __launch_bounds__(256) void g1_kernel(
    const ushort_t* __restrict__ aggb, const ushort_t* __restrict__ xb,
    const ushort_t* __restrict__ Wb1, const float* __restrict__ b1,
    ushort_t* __restrict__ h1b) {
    __shared__ short8 wl8[2048];                 // 32 KB
    ushort_t* wl = (ushort_t*)wl8;
#pragma unroll
    for (int it = 0; it < 8; it++) {
        int q = it * 256 + threadIdx.x;
        int n = q >> 4, c = q & 15;
        short8 v = ((const short8*)Wb1)[q];
        *(short8*)(wl + n * HID + ((c ^ (n & 7)) << 3)) = v;
    }
    __syncthreads();

    int wave = threadIdx.x >> 6;
    int lane = threadIdx.x & 63;
    int nb = blockIdx.x * 128 + wave * 32;
    if (nb >= N_NODES) return;   // after the only barrier
    int half = lane >> 5, col = lane & 31;
    int nA = nb + col;
    if (nA >= N_NODES) nA = N_NODES - 1;

    short8 areg[8];
#pragma unroll
    for (int s = 0; s < 4; s++)
        areg[s] = *(const short8*)(aggb + (size_t)nA * FIN + s * 16 + half * 8);
#pragma unroll
    for (int s = 4; s < 8; s++)
        areg[s] = *(const short8*)(xb + (size_t)nA * FIN + (s - 4) * 16 + half * 8);

    fx16 acc[4];
#pragma unroll
    for (int jt = 0; jt < 4; jt++)
#pragma unroll
        for (int r = 0; r < 16; r++) acc[jt][r] = 0.f;

#pragma unroll
    for (int s = 0; s < 8; s++) {
        int c = 2 * s + half;
#pragma unroll
        for (int jt = 0; jt < 4; jt++) {
            int n = jt * 32 + col;
            short8 bq = *(const short8*)(wl + n * HID + ((c ^ (n & 7)) << 3));
            acc[jt] = __builtin_amdgcn_mfma_f32_32x32x16_bf16(areg[s], bq, acc[jt], 0, 0, 0);
        }
    }
#pragma unroll
    for (int jt = 0; jt < 4; jt++) {
        int j = jt * 32 + col;
        float bias = b1[j];
#pragma unroll
        for (int r = 0; r < 16; r++) {
            int node = nb + (r & 3) + 8 * (r >> 2) + 4 * half;
            if (node < N_NODES) {
                float v = acc[jt][r] + bias;
                v = v > 0.f ? v : __expf(v) - 1.f;
                h1b[(size_t)node * HID + j] = f2bf(v);
            }
        }
    }
}

// ------- MFMA GEMM layer 2 + MFMA MLP head -------
// LDS (43008 B, 3 blocks/CU):
//   [0..32768)      Wb2 K-half staging (32 KB, two passes), later t2 tile
//   [0..34816)      t2 tile [node][feature], stride 136 ushorts (16B-aligned rows)
//   [34816..43008)  Wfc1 padded 32x128 bf16, XOR-swizzled (disjoint from Wb2 region)
// Head: fc1 as 8 MFMAs on the tile, relu*Wfc2 per lane, 5-round shfl_xor butterfly.
__global__ __launch_bounds__(256) void g2h_kernel(
    const ushort_t* __restrict__ agg2b, const ushort_t* __restrict__ h1b,
    const ushort_t* __restrict__ Wb2, const float* __restrict__ b2,
    const float* __restrict__ Wfc1, const float* __restrict__ bfc1,
    const float* __restrict__ Wfc2, const float* __restrict__ bfc2,
    float* __restrict__ out) {
    __shared__ ushort_t smem[21504];             // 43008 B
    ushort_t* wl = smem;                         // 16384 ushorts (32 KB)
    ushort_t* wf = smem + 17408;                 // 4096 ushorts (8 KB)

    // stage Wfc1b once (region never touched by Wb2/tile)
#pragma unroll
    for (int it = 0; it < 16; it++) {
        int idx = it * 256 + threadIdx.x;        // 0..4095
        int m = idx >> 7, k = idx & 127;
        float v = (m < 20) ? Wfc1[m * HID + k] : 0.f;
        wf[m * 128 + (((k >> 3) ^ (m & 7)) << 3) + (k & 7)] = f2bf(v);
    }
    // stage Wb2 K-half 0 (cols 0..127)
#pragma unroll
    for (int it = 0; it < 8; it++) {
        int q = it * 256 + threadIdx.x;          // 0..2047
        int n = q >> 4, c = q & 15;
        short8 v = *(const short8*)(Wb2 + (size_t)n * 256 + c * 8);
        *(short8*)(wl + n * 128 + ((c ^ (n & 7)) << 3)) = v;
    }

    int wave = threadIdx.x >> 6;
    int lane = threadIdx.x & 63;
    int half = lane >> 5, col = lane & 31;
    int nb = blockIdx.x * 128 + wave * 32;       // tail waves keep running (barriers!)
    int nA = nb + col;
    if (nA >= N_NODES) nA = N_NODES - 1;

    short8 areg[16];
#pragma unroll
    for (int s = 0; s < 8; s++)
        areg[s] = *(const short8*)(agg2b + (size_t)nA * HID + s * 16 + half * 8);
#pragma unroll
    for (int s = 8; s < 16; s++)
        areg[s] = *(const short8*)(h1b + (size_t)nA * HID + (s - 8) * 16 + half * 8);

    fx16 acc[4];
#pragma unroll
    for (int jt = 0; jt < 4; jt++)
#pragma unroll
        for (int r = 0; r < 16; r++) acc[jt][r] = 0.f;

    __syncthreads();
#pragma unroll
    for (int s = 0; s < 8; s++) {                // K 0..127 (agg2 part)
        int c = 2 * s + half;
#pragma unroll
        for (int jt = 0; jt < 4; jt++) {
            int n = jt * 32 + col;
            short8 bq = *(const short8*)(wl + n * 128 + ((c ^ (n & 7)) << 3));
            acc[jt] = __builtin_amdgcn_mfma_f32_32x32x16_bf16(areg[s], bq, acc[jt], 0, 0, 0);
        }
    }
    __syncthreads();
    // stage Wb2 K-half 1 (cols 128..255)
#pragma unroll
    for (int it = 0; it < 8; it++) {
        int q = it * 256 + threadIdx.x;
        int n = q >> 4, c = q & 15;
        short8 v = *(const short8*)(Wb2 + (size_t)n * 256 + 128 + c * 8);
        *(short8*)(wl + n * 128 + ((c ^ (n & 7)) << 3)) = v;
    }
    __syncthreads();
#pragma unroll
    for (int s = 8; s < 16; s++) {               // K 128..255 (h1 part)
        int c = 2 * (s - 8) + half;
#pragma unroll
        for (int jt = 0; jt < 4; jt++) {
            int n = jt * 32 + col;
            short8 bq = *(const short8*)(wl + n * 128 + ((c ^ (n & 7)) << 3));
            acc[jt] = __builtin_amdgcn_mfma_f32_32x32x16_bf16(areg[s], bq, acc[jt], 0, 0, 0);
        }
    }
    __syncthreads();   // weights dead; reuse [0..34816) as t2 tile

    // t2 tile [node_local][feature], stride 136 ushorts
    ushort_t* tl = smem;
#pragma unroll
    for (int jt = 0; jt < 4; jt++) {
        int j = jt * 32 + col;
        float bias = b2[j];
#pragma unroll
        for (int r = 0; r < 16; r++) {
            int nl = wave * 32 + (r & 3) + 8 * (r >> 2) + 4 * half;
            tl[nl * 136 + j] = f2bf(acc[jt][r] + bias);
        }
    }
    __syncthreads();

    // fc1 as MFMA: A = t2 tile rows (node m = wave*32+col), B = Wfc1b (row col)
    short8 af[8];
#pragma unroll
    for (int s = 0; s < 8; s++)
        af[s] = *(const short8*)(tl + (wave * 32 + col) * 136 + s * 16 + half * 8);
    fx16 fa;
#pragma unroll
    for (int r = 0; r < 16; r++) fa[r] = 0.f;
#pragma unroll
    for (int s = 0; s < 8; s++) {
        int c = 2 * s + half;
        short8 bw = *(const short8*)(wf + col * 128 + ((c ^ (col & 7)) << 3));
        fa = __builtin_amdgcn_mfma_f32_32x32x16_bf16(af[s], bw, fa, 0, 0, 0);
    }
    // epilogue: relu(+bfc1) * Wfc2, butterfly-sum over the 32 output cols
    float biasv = (col < 20) ? bfc1[col] : 0.f;
    float w2v = (col < 20) ? Wfc2[col] : 0.f;
    float bz = bfc2[0];
    float red[16];
#pragma unroll
    for (int r = 0; r < 16; r++) {
        float v = fa[r] + biasv;
        v = (v > 0.f ? v : 0.f) * w2v;
        v += __shfl_xor(v, 1);
        v += __shfl_xor(v, 2);
        v += __shfl_xor(v, 4);
        v += __shfl_xor(v, 8);
        v += __shfl_xor(v, 16);
        red[r] = v;
    }
    if (col == 0) {
#pragma unroll
        for (int r = 0; r < 16; r++) {
            int nl = wave * 32 + (r & 3) + 8 * (r >> 2) + 4 * half;
            int ng = blockIdx.x * 128 + nl;
            if (ng < N_NODES) out[ng] = red[r] + bz;
        }
    }
}

// ---------------- launch ----------------
extern "C" void kernel_launch(void* const* d_in, const int* in_sizes, int n_in,
                              void* d_out, int out_size, void* d_ws, size_t ws_size,
                              hipStream_t stream) {
    const float* x = (const float*)d_in[0];
    const int* ei = (const int*)d_in[1];
    const float* W1rel = (const float*)d_in[2];
    const float* b1 = (const float*)d_in[3];
    const float* W1root = (const float*)d_in[4];
    const float* W2rel = (const float*)d_in[5];
    const float* b2 = (const float*)d_in[6];
    const float* W2root = (const float*)d_in[7];
    const float* Wfc1 = (const float*)d_in[8];
    const float* bfc1 = (const float*)d_in[9];
    const float* Wfc2 = (const float*)d_in[10];
    const float* bfc2 = (const float*)d_in[11];
    float* out = (float*)d_out;

    char* ws = (char*)d_ws;
    size_t o = 0;
    int* deg = (int*)(ws + o);       o += (size_t)N_NODES * 4;
    int* off = (int*)(ws + o);       o += (size_t)(N_NODES + 1) * 4 + 12;
    int* bsums = (int*)(ws + o);     o += 4096;
    int* flag = (int*)(ws + o);      o += 16;
    int* rank = (int*)(ws + o);      o += (size_t)N_EDGES * 4;                  // 3.2 MB
    int* srcs = (int*)(ws + o);      o += (size_t)SRCS_CAP * 4;                 // 6.0 MB
    ushort_t* xb = (ushort_t*)(ws + o);    o += (size_t)(N_NODES + 1) * FIN * 2;  // 12.8 MB (+zero row)
    ushort_t* agg1b = (ushort_t*)(ws + o); o += (size_t)N_NODES * FIN * 2;        // 12.8 MB
    ushort_t* h1b = (ushort_t*)(ws + o);   o += (size_t)(N_NODES + 1) * HID * 2;  // 25.6 MB (+zero row)
    ushort_t* agg2b = (ushort_t*)(ws + o); o += (size_t)N_NODES * HID * 2;        // 25.6 MB
    ushort_t* Wb1 = (ushort_t*)(ws + o);   o += (size_t)HID * HID * 2;            // 32 KB
    ushort_t* Wb2 = (ushort_t*)(ws + o);   o += (size_t)HID * 2 * HID * 2;        // 64 KB

    const int GW = (N_NODES + 127) / 128; // 782 blocks: 4 waves x 32 nodes

    zero_int_kernel<<<NB1, 256, 0, stream>>>(deg, flag, srcs);
    detect_kernel<<<32, 256, 0, stream>>>(ei, flag);
    hist_kernel<<<(N_EDGES + 255) / 256, 256, 0, stream>>>(ei, flag, deg, rank);
    scan1_kernel<<<NB1, 256, 0, stream>>>(deg, off, bsums);
    scan2_kernel<<<1, 512, 0, stream>>>(bsums);
    scan3_kernel<<<NB1, 256, 0, stream>>>(off, bsums);
    scatter_kernel<<<(N_EDGES + 255) / 256, 256, 0, stream>>>(ei, flag, off, rank, srcs);
    cvt_kernel<<<(N_NODES * FIN / 4 + 255) / 256, 256, 0, stream>>>(
        x, xb, W1rel, W1root, W2rel, W2root, Wb1, Wb2, h1b);
    agg1_kernel<<<N_NODES / 4, 256, 0, stream>>>(xb, off, srcs, agg1b);
    g1_kernel<<<GW, 256, 0, stream>>>(agg1b, xb, Wb1, b1, h1b);
    agg2_kernel<<<N_NODES / 4, 256, 0, stream>>>(h1b, off, srcs, agg2b);
    g2h_kernel<<<GW, 256, 0, stream>>>(agg2b, h1b, Wb2, b2, Wfc1, bfc1, Wfc2, bfc2, out);
}

// Round 4
// 270.056 us; speedup vs baseline: 1.2723x; 1.0302x over previous
//
#include <hip/hip_runtime.h>

#define N_NODES 100000
#define N_EDGES 800000
#define FIN 64
#define HID 128
#define NB1 391   // ceil(N_NODES/256)
#define SRCS_CAP (N_EDGES + 7 * N_NODES)   // padded CSR capacity (pad to multiple of 8 per node)

typedef unsigned short ushort_t;
typedef __attribute__((ext_vector_type(8))) short short8;   // 8 bf16 = 4 VGPRs (MFMA A/B frag)
typedef __attribute__((ext_vector_type(16))) float fx16;    // 32x32 MFMA C/D frag
typedef __attribute__((ext_vector_type(4))) unsigned short us4;

__device__ inline ushort_t f2bf(float f) {   // RNE fp32 -> bf16
    unsigned u = __float_as_uint(f);
    u += 0x7fffu + ((u >> 16) & 1u);
    return (ushort_t)(u >> 16);
}
__device__ inline float bf2f(ushort_t h) { return __uint_as_float(((unsigned)h) << 16); }

__device__ inline void upadd(float* acc, uint4 A) {   // accumulate 8 bf16 of a 16B chunk
    acc[0] += __uint_as_float(A.x << 16);
    acc[1] += __uint_as_float(A.x & 0xffff0000u);
    acc[2] += __uint_as_float(A.y << 16);
    acc[3] += __uint_as_float(A.y & 0xffff0000u);
    acc[4] += __uint_as_float(A.z << 16);
    acc[5] += __uint_as_float(A.z & 0xffff0000u);
    acc[6] += __uint_as_float(A.w << 16);
    acc[7] += __uint_as_float(A.w & 0xffff0000u);
}

// ---------------- utility ----------------
// zero deg + flag, fill padded srcs with sentinel row N_NODES (zero row)
__global__ void zero_int_kernel(int* __restrict__ deg, int* __restrict__ flag,
                                int* __restrict__ srcs) {
    int i = blockIdx.x * 256 + threadIdx.x;
    if (i < N_NODES) deg[i] = 0;
    if (i == 0) *flag = 0;
    for (int k = i; k < SRCS_CAP; k += NB1 * 256) srcs[k] = N_NODES;
}

// int32 vs int64 edge_index layout probe (int64 little-endian => odd words all 0)
__global__ void detect_kernel(const int* __restrict__ w, int* __restrict__ flag) {
    int i = blockIdx.x * 256 + threadIdx.x;
    if (i < 8192) {
        if (w[2 * i + 1] != 0) atomicOr(flag, 1);
    }
}

// ---------------- CSR build (padded to multiple of 8 per node) ----------------
__global__ void hist_kernel(const int* __restrict__ w, const int* __restrict__ flag,
                            int* __restrict__ deg, int* __restrict__ rank) {
    int e = blockIdx.x * 256 + threadIdx.x;
    if (e >= N_EDGES) return;
    int is32 = *flag;
    int d = is32 ? w[N_EDGES + e] : w[2 * (N_EDGES + e)];
    rank[e] = atomicAdd(&deg[d], 1);
}

__global__ void scan1_kernel(const int* __restrict__ deg, int* __restrict__ off,
                             int* __restrict__ bsums) {
    __shared__ int s[256];
    int t = threadIdx.x;
    int i = blockIdx.x * 256 + t;
    int v = (i < N_NODES) ? ((deg[i] + 7) & ~7) : 0;   // padded degree
    s[t] = v;
    __syncthreads();
    for (int d = 1; d < 256; d <<= 1) {
        int w = (t >= d) ? s[t - d] : 0;
        __syncthreads();
        s[t] += w;
        __syncthreads();
    }
    if (i < N_NODES) off[i] = s[t] - v;
    if (t == 255) bsums[blockIdx.x] = s[255];
}

__global__ void scan2_kernel(int* __restrict__ bsums) {
    __shared__ int s[512];
    int t = threadIdx.x;
    int v = (t < NB1) ? bsums[t] : 0;
    s[t] = v;
    __syncthreads();
    for (int d = 1; d < 512; d <<= 1) {
        int w = (t >= d) ? s[t - d] : 0;
        __syncthreads();
        s[t] += w;
        __syncthreads();
    }
    if (t < NB1) bsums[t] = s[t] - v;
    if (t == NB1 - 1) bsums[NB1] = s[t];   // total padded edge count
}

__global__ void scan3_kernel(int* __restrict__ off, const int* __restrict__ bsums) {
    int i = blockIdx.x * 256 + threadIdx.x;
    if (i < N_NODES) off[i] = off[i] + bsums[blockIdx.x];
    if (i == 0) off[N_NODES] = bsums[NB1];
}

__global__ void scatter_kernel(const int* __restrict__ w, const int* __restrict__ flag,
                               const int* __restrict__ off, const int* __restrict__ rank,
                               int* __restrict__ srcs) {
    int e = blockIdx.x * 256 + threadIdx.x;
    if (e >= N_EDGES) return;
    int is32 = *flag;
    int s = is32 ? w[e] : w[2 * e];
    int d = is32 ? w[N_EDGES + e] : w[2 * (N_EDGES + e)];
    srcs[off[d] + rank[e]] = s;
}

// ---------------- dtype conversion + sentinel zero rows ----------------
// Wb1[n][k], k<64 -> W1rel, else W1root. Wb2[n][k], k<128 -> W2rel, else W2root.
__global__ void cvt_kernel(const float* __restrict__ x, ushort_t* __restrict__ xb,
                           const float* __restrict__ W1rel, const float* __restrict__ W1root,
                           const float* __restrict__ W2rel, const float* __restrict__ W2root,
                           ushort_t* __restrict__ Wb1, ushort_t* __restrict__ Wb2,
                           ushort_t* __restrict__ h1b) {
    int i = blockIdx.x * 256 + threadIdx.x; // quad id for x
    if (i < N_NODES * FIN / 4) {
        float4 v = ((const float4*)x)[i];
        us4 o = {f2bf(v.x), f2bf(v.y), f2bf(v.z), f2bf(v.w)};
        ((us4*)xb)[i] = o;
    }
    us4 z = {0, 0, 0, 0};
    if (i < 16) ((us4*)xb)[(size_t)N_NODES * 16 + i] = z;          // xb zero row
    if (i >= 16 && i < 48) ((us4*)h1b)[(size_t)N_NODES * 32 + (i - 16)] = z;  // h1b zero row
    if (i < HID * HID) {
        int n = i >> 7, k = i & 127;
        float v = (k < FIN) ? W1rel[n * FIN + k] : W1root[n * FIN + (k - FIN)];
        Wb1[i] = f2bf(v);
    }
    if (i < HID * 2 * HID) {
        int n = i >> 8, k = i & 255;
        float v = (k < HID) ? W2rel[n * HID + k] : W2root[n * HID + (k - HID)];
        Wb2[i] = f2bf(v);
    }
}

// ------- aggregation: 2 nodes per wave, maskless padded gather, high MLP -------
// agg1: each 32-lane half = one node; 4 edge slots x 8 chunks (16B) of the 128B row.
// Per loop iteration (step 8): 2 independent row-gathers per node, 4 per wave.
__global__ void agg1_kernel(const ushort_t* __restrict__ xb, const int* __restrict__ off,
                            const int* __restrict__ srcs, ushort_t* __restrict__ aggb) {
    int wpair = (blockIdx.x * 256 + threadIdx.x) >> 6;   // wave id -> node pair
    int lane = threadIdx.x & 63;
    int n0 = wpair * 2;
    if (n0 >= N_NODES) return;
    int2 ov = *(const int2*)(off + n0);                  // off[n0], off[n0+1]
    int em = off[n0 + 2];
    int b0 = __builtin_amdgcn_readfirstlane(ov.x);
    int e0 = __builtin_amdgcn_readfirstlane(ov.y);
    int e1 = __builtin_amdgcn_readfirstlane(em);
    int hsel = lane >> 5;                                // node select
    unsigned g = (lane >> 3) & 3;                        // slot 0..3
    unsigned c = lane & 7;                               // 16B chunk of 128B row
    int b = hsel ? e0 : b0;
    int e = hsel ? e1 : e0;
    float acc[8];
#pragma unroll
    for (int j = 0; j < 8; j++) acc[j] = 0.f;
    const uint4* rows = (const uint4*)xb;                // 8 chunks per row (incl. zero row N)
    for (int p = b; p < e; p += 8) {
        unsigned s0 = (unsigned)srcs[p + g];             // padding => always valid
        unsigned s1 = (unsigned)srcs[p + 4 + g];
        uint4 A = rows[s0 * 8u + c];
        uint4 B = rows[s1 * 8u + c];
        upadd(acc, A);
        upadd(acc, B);
    }
#pragma unroll
    for (int j = 0; j < 8; j++) {
        acc[j] += __shfl_xor(acc[j], 8);
        acc[j] += __shfl_xor(acc[j], 16);
    }
    if ((lane & 31) < 8) {
        unsigned w0 = (unsigned)f2bf(acc[0]) | ((unsigned)f2bf(acc[1]) << 16);
        unsigned w1 = (unsigned)f2bf(acc[2]) | ((unsigned)f2bf(acc[3]) << 16);
        unsigned w2 = (unsigned)f2bf(acc[4]) | ((unsigned)f2bf(acc[5]) << 16);
        unsigned w3 = (unsigned)f2bf(acc[6]) | ((unsigned)f2bf(acc[7]) << 16);
        uint4 o = {w0, w1, w2, w3};
        ((uint4*)(aggb + (size_t)(n0 + hsel) * FIN))[c] = o;
    }
}

// agg2: each 32-lane half = one node; 2 slot-parities x 16 chunks (16B) of the 256B row.
// Per loop iteration (step 8): 4 independent row-gathers per node, 8 per wave.
__global__ void agg2_kernel(const ushort_t* __restrict__ h1b, const int* __restrict__ off,
                            const int* __restrict__ srcs, ushort_t* __restrict__ aggb) {
    int wpair = (blockIdx.x * 256 + threadIdx.x) >> 6;   // wave id -> node pair
    int lane = threadIdx.x & 63;
    int n0 = wpair * 2;
    if (n0 >= N_NODES) return;
    int2 ov = *(const int2*)(off + n0);
    int em = off[n0 + 2];
    int b0 = __builtin_amdgcn_readfirstlane(ov.x);
    int e0 = __builtin_amdgcn_readfirstlane(ov.y);
    int e1 = __builtin_amdgcn_readfirstlane(em);
    int hsel = lane >> 5;                                // node select
    unsigned g = (lane >> 4) & 1;                        // slot parity 0/1
    unsigned c = lane & 15;                              // 16B chunk of 256B row
    int b = hsel ? e0 : b0;
    int e = hsel ? e1 : e0;
    float acc[8];
#pragma unroll
    for (int j = 0; j < 8; j++) acc[j] = 0.f;
    const uint4* rows = (const uint4*)h1b;               // 16 chunks per row (incl. zero row N)
    for (int p = b; p < e; p += 8) {
        unsigned s0 = (unsigned)srcs[p + g];
        unsigned s1 = (unsigned)srcs[p + 2 + g];
        unsigned s2 = (unsigned)srcs[p + 4 + g];
        unsigned s3 = (unsigned)srcs[p + 6 + g];
        uint4 A = rows[s0 * 16u + c];
        uint4 B = rows[s1 * 16u + c];
        uint4 C = rows[s2 * 16u + c];
        uint4 D = rows[s3 * 16u + c];
        upadd(acc, A);
        upadd(acc, B);
        upadd(acc, C);
        upadd(acc, D);
    }
#pragma unroll
    for (int j = 0; j < 8; j++) acc[j] += __shfl_xor(acc[j], 16);
    if ((lane & 31) < 16) {
        unsigned w0 = (unsigned)f2bf(acc[0]) | ((unsigned)f2bf(acc[1]) << 16);
        unsigned w1 = (unsigned)f2bf(acc[2]) | ((unsigned)f2bf(acc[3]) << 16);
        unsigned w2 = (unsigned)f2bf(acc[4]) | ((unsigned)f2bf(acc[5]) << 16);
        unsigned w3 = (unsigned)f2bf(acc[6]) | ((unsigned)f2bf(acc[7]) << 16);
        uint4 o = {w0, w1, w2, w3};
        ((uint4*)(aggb + (size_t)(n0 + hsel) * HID))[c] = o;
    }
}

// ------- MFMA GEMM layer 1: h1 = elu([agg1,x] @ Wb1^T + b1) -------
__global__ __launch_bounds__(256) void g1_kernel(
    const ushort_t* __restrict__ aggb, const ushort_t* __restrict__ xb,
    const ushort_t* __restrict__ Wb1, const float* __restrict__ b1,
    ushort_t* __restrict__ h1b) {
    __shared__ short8 wl8[2048];                 // 32 KB
    ushort_t* wl = (ushort_t*)wl8;
#pragma unroll
    for (int it = 0; it < 8; it++) {
        int q = it * 256 + threadIdx.x;
        int n = q >> 4, c = q & 15;
        short8 v = ((const short8*)Wb1)[q];
        *(short8*)(wl + n * HID + ((c ^ (n & 7)) << 3)) = v;
    }
    __syncthreads();

    int wave = threadIdx.x >> 6;
    int lane = threadIdx.x & 63;
    int nb = blockIdx.x * 128 + wave * 32;
    if (nb >= N_NODES) return;   // after the only barrier
    int half = lane >> 5, col = lane & 31;
    int nA = nb + col;
    if (nA >= N_NODES) nA = N_NODES - 1;

    short8 areg[8];
#pragma unroll
    for (int s = 0; s < 4; s++)
        areg[s] = *(const short8*)(aggb + (size_t)nA * FIN + s * 16 + half * 8);
#pragma unroll
    for (int s = 4; s < 8; s++)
        areg[s] = *(const short8*)(xb + (size_t)nA * FIN + (s - 4) * 16 + half * 8);

    fx16 acc[4];
#pragma unroll
    for (int jt = 0; jt < 4; jt++)
#pragma unroll
        for (int r = 0; r < 16; r++) acc[jt][r] = 0.f;

#pragma unroll
    for (int s = 0; s < 8; s++) {
        int c = 2 * s + half;
#pragma unroll
        for (int jt = 0; jt < 4; jt++) {
            int n = jt * 32 + col;
            short8 bq = *(const short8*)(wl + n * HID + ((c ^ (n & 7)) << 3));
            acc[jt] = __builtin_amdgcn_mfma_f32_32x32x16_bf16(areg[s], bq, acc[jt], 0, 0, 0);
        }
    }
#pragma unroll
    for (int jt = 0; jt < 4; jt++) {
        int j = jt * 32 + col;
        float bias = b1[j];
#pragma unroll
        for (int r = 0; r < 16; r++) {
            int node = nb + (r & 3) + 8 * (r >> 2) + 4 * half;
            if (node < N_NODES) {
                float v = acc[jt][r] + bias;
                v = v > 0.f ? v : __expf(v) - 1.f;
                h1b[(size_t)node * HID + j] = f2bf(v);
            }
        }
    }
}

// ------- MFMA GEMM layer 2 + MFMA MLP head -------
// LDS (43008 B, 3 blocks/CU):
//   [0..32768)      Wb2 K-half staging (32 KB, two passes), later t2 tile
//   [0..34816)      t2 tile [node][feature], stride 136 ushorts (16B-aligned rows)
//   [34816..43008)  Wfc1 padded 32x128 bf16, XOR-swizzled (disjoint from Wb2 region)
// Head: fc1 as 8 MFMAs on the tile, relu*Wfc2 per lane, 5-round shfl_xor butterfly.
__global__ __launch_bounds__(256) void g2h_kernel(
    const ushort_t* __restrict__ agg2b, const ushort_t* __restrict__ h1b,
    const ushort_t* __restrict__ Wb2, const float* __restrict__ b2,
    const float* __restrict__ Wfc1, const float* __restrict__ bfc1,
    const float* __restrict__ Wfc2, const float* __restrict__ bfc2,
    float* __restrict__ out) {
    __shared__ ushort_t smem[21504];             // 43008 B
    ushort_t* wl = smem;                         // 16384 ushorts (32 KB)
    ushort_t* wf = smem + 17408;                 // 4096 ushorts (8 KB)

    // stage Wfc1b once (region never touched by Wb2/tile)
#pragma unroll
    for (int it = 0; it < 16; it++) {
        int idx = it * 256 + threadIdx.x;        // 0..4095
        int m = idx >> 7, k = idx & 127;
        float v = (m < 20) ? Wfc1[m * HID + k] : 0.f;
        wf[m * 128 + (((k >> 3) ^ (m & 7)) << 3) + (k & 7)] = f2bf(v);
    }
    // stage Wb2 K-half 0 (cols 0..127)
#pragma unroll
    for (int it = 0; it < 8; it++) {
        int q = it * 256 + threadIdx.x;          // 0..2047
        int n = q >> 4, c = q & 15;
        short8 v = *(const short8*)(Wb2 + (size_t)n * 256 + c * 8);
        *(short8*)(wl + n * 128 + ((c ^ (n & 7)) << 3)) = v;
    }

    int wave = threadIdx.x >> 6;
    int lane = threadIdx.x & 63;
    int half = lane >> 5, col = lane & 31;
    int nb = blockIdx.x * 128 + wave * 32;       // tail waves keep running (barriers!)
    int nA = nb + col;
    if (nA >= N_NODES) nA = N_NODES - 1;

    short8 areg[16];
#pragma unroll
    for (int s = 0; s < 8; s++)
        areg[s] = *(const short8*)(agg2b + (size_t)nA * HID + s * 16 + half * 8);
#pragma unroll
    for (int s = 8; s < 16; s++)
        areg[s] = *(const short8*)(h1b + (size_t)nA * HID + (s - 8) * 16 + half * 8);

    fx16 acc[4];
#pragma unroll
    for (int jt = 0; jt < 4; jt++)
#pragma unroll
        for (int r = 0; r < 16; r++) acc[jt][r] = 0.f;

    __syncthreads();
#pragma unroll
    for (int s = 0; s < 8; s++) {                // K 0..127 (agg2 part)
        int c = 2 * s + half;
#pragma unroll
        for (int jt = 0; jt < 4; jt++) {
            int n = jt * 32 + col;
            short8 bq = *(const short8*)(wl + n * 128 + ((c ^ (n & 7)) << 3));
            acc[jt] = __builtin_amdgcn_mfma_f32_32x32x16_bf16(areg[s], bq, acc[jt], 0, 0, 0);
        }
    }
    __syncthreads();
    // stage Wb2 K-half 1 (cols 128..255)
#pragma unroll
    for (int it = 0; it < 8; it++) {
        int q = it * 256 + threadIdx.x;
        int n = q >> 4, c = q & 15;
        short8 v = *(const short8*)(Wb2 + (size_t)n * 256 + 128 + c * 8);
        *(short8*)(wl + n * 128 + ((c ^ (n & 7)) << 3)) = v;
    }
    __syncthreads();
#pragma unroll
    for (int s = 8; s < 16; s++) {               // K 128..255 (h1 part)
        int c = 2 * (s - 8) + half;
#pragma unroll
        for (int jt = 0; jt < 4; jt++) {
            int n = jt * 32 + col;
            short8 bq = *(const short8*)(wl + n * 128 + ((c ^ (n & 7)) << 3));
            acc[jt] = __builtin_amdgcn_mfma_f32_32x32x16_bf16(areg[s], bq, acc[jt], 0, 0, 0);
        }
    }
    __syncthreads();   // weights dead; reuse [0..34816) as t2 tile

    // t2 tile [node_local][feature], stride 136 ushorts
    ushort_t* tl = smem;
#pragma unroll
    for (int jt = 0; jt < 4; jt++) {
        int j = jt * 32 + col;
        float bias = b2[j];
#pragma unroll
        for (int r = 0; r < 16; r++) {
            int nl = wave * 32 + (r & 3) + 8 * (r >> 2) + 4 * half;
            tl[nl * 136 + j] = f2bf(acc[jt][r] + bias);
        }
    }
    __syncthreads();

    // fc1 as MFMA: A = t2 tile rows (node m = wave*32+col), B = Wfc1b (row col)
    short8 af[8];
#pragma unroll
    for (int s = 0; s < 8; s++)
        af[s] = *(const short8*)(tl + (wave * 32 + col) * 136 + s * 16 + half * 8);
    fx16 fa;
#pragma unroll
    for (int r = 0; r < 16; r++) fa[r] = 0.f;
#pragma unroll
    for (int s = 0; s < 8; s++) {
        int c = 2 * s + half;
        short8 bw = *(const short8*)(wf + col * 128 + ((c ^ (col & 7)) << 3));
        fa = __builtin_amdgcn_mfma_f32_32x32x16_bf16(af[s], bw, fa, 0, 0, 0);
    }
    // epilogue: relu(+bfc1) * Wfc2, butterfly-sum over the 32 output cols
    float biasv = (col < 20) ? bfc1[col] : 0.f;
    float w2v = (col < 20) ? Wfc2[col] : 0.f;
    float bz = bfc2[0];
    float red[16];
#pragma unroll
    for (int r = 0; r < 16; r++) {
        float v = fa[r] + biasv;
        v = (v > 0.f ? v : 0.f) * w2v;
        v += __shfl_xor(v, 1);
        v += __shfl_xor(v, 2);
        v += __shfl_xor(v, 4);
        v += __shfl_xor(v, 8);
        v += __shfl_xor(v, 16);
        red[r] = v;
    }
    if (col == 0) {
#pragma unroll
        for (int r = 0; r < 16; r++) {
            int nl = wave * 32 + (r & 3) + 8 * (r >> 2) + 4 * half;
            int ng = blockIdx.x * 128 + nl;
            if (ng < N_NODES) out[ng] = red[r] + bz;
        }
    }
}

// ---------------- launch ----------------
extern "C" void kernel_launch(void* const* d_in, const int* in_sizes, int n_in,
                              void* d_out, int out_size, void* d_ws, size_t ws_size,
                              hipStream_t stream) {
    const float* x = (const float*)d_in[0];
    const int* ei = (const int*)d_in[1];
    const float* W1rel = (const float*)d_in[2];
    const float* b1 = (const float*)d_in[3];
    const float* W1root = (const float*)d_in[4];
    const float* W2rel = (const float*)d_in[5];
    const float* b2 = (const float*)d_in[6];
    const float* W2root = (const float*)d_in[7];
    const float* Wfc1 = (const float*)d_in[8];
    const float* bfc1 = (const float*)d_in[9];
    const float* Wfc2 = (const float*)d_in[10];
    const float* bfc2 = (const float*)d_in[11];
    float* out = (float*)d_out;

    char* ws = (char*)d_ws;
    size_t o = 0;
    int* deg = (int*)(ws + o);       o += (size_t)N_NODES * 4;
    int* off = (int*)(ws + o);       o += (size_t)(N_NODES + 1) * 4 + 12;
    int* bsums = (int*)(ws + o);     o += 4096;
    int* flag = (int*)(ws + o);      o += 16;
    int* rank = (int*)(ws + o);      o += (size_t)N_EDGES * 4;                  // 3.2 MB
    int* srcs = (int*)(ws + o);      o += (size_t)SRCS_CAP * 4;                 // 6.0 MB
    ushort_t* xb = (ushort_t*)(ws + o);    o += (size_t)(N_NODES + 1) * FIN * 2;  // 12.8 MB (+zero row)
    ushort_t* agg1b = (ushort_t*)(ws + o); o += (size_t)N_NODES * FIN * 2;        // 12.8 MB
    ushort_t* h1b = (ushort_t*)(ws + o);   o += (size_t)(N_NODES + 1) * HID * 2;  // 25.6 MB (+zero row)
    ushort_t* agg2b = (ushort_t*)(ws + o); o += (size_t)N_NODES * HID * 2;        // 25.6 MB
    ushort_t* Wb1 = (ushort_t*)(ws + o);   o += (size_t)HID * HID * 2;            // 32 KB
    ushort_t* Wb2 = (ushort_t*)(ws + o);   o += (size_t)HID * 2 * HID * 2;        // 64 KB

    const int GW = (N_NODES + 127) / 128; // 782 blocks: 4 waves x 32 nodes
    const int GA = N_NODES / 8;           // 12500 blocks: 4 waves x 2 nodes each

    zero_int_kernel<<<NB1, 256, 0, stream>>>(deg, flag, srcs);
    detect_kernel<<<32, 256, 0, stream>>>(ei, flag);
    hist_kernel<<<(N_EDGES + 255) / 256, 256, 0, stream>>>(ei, flag, deg, rank);
    scan1_kernel<<<NB1, 256, 0, stream>>>(deg, off, bsums);
    scan2_kernel<<<1, 512, 0, stream>>>(bsums);
    scan3_kernel<<<NB1, 256, 0, stream>>>(off, bsums);
    scatter_kernel<<<(N_EDGES + 255) / 256, 256, 0, stream>>>(ei, flag, off, rank, srcs);
    cvt_kernel<<<(N_NODES * FIN / 4 + 255) / 256, 256, 0, stream>>>(
        x, xb, W1rel, W1root, W2rel, W2root, Wb1, Wb2, h1b);
    agg1_kernel<<<GA, 256, 0, stream>>>(xb, off, srcs, agg1b);
    g1_kernel<<<GW, 256, 0, stream>>>(agg1b, xb, Wb1, b1, h1b);
    agg2_kernel<<<GA, 256, 0, stream>>>(h1b, off, srcs, agg2b);
    g2h_kernel<<<GW, 256, 0, stream>>>(agg2b, h1b, Wb2, b2, Wfc1, bfc1, Wfc2, bfc2, out);
}